// Round 7
// baseline (176.432 us; speedup 1.0000x reference)
//
#include <hip/hip_runtime.h>
#include <hip/hip_bf16.h>

typedef unsigned short u16;
typedef unsigned int   u32;
typedef __attribute__((ext_vector_type(8))) short  bf16x8;
typedef __attribute__((ext_vector_type(4))) float  floatx4;

#define NB 2
#define NT 4
#define CK 64
#define CV 256
#define HH 64
#define WW 64
#define MM 4096    // NT*32*32
#define NN 4096    // HH*WW
#define SCALE 0.125f
#define SHIFT 4.0f
#define OUT_B 2097152      // f32 elems per batch in out (512*4096)
#define MSPLIT 2
#define MHALF 2048
#define ITERS 16           // MHALF / 128

__device__ __forceinline__ u16 f2b(float f) {
    __hip_bfloat16 h = __float2bfloat16(f);
    union { __hip_bfloat16 h; u16 u; } v; v.h = h; return v.u;
}

// ============================ fast (MFMA) path ============================

// fused: K -> pk[(b*MM+m)*CK+c] ; V -> vt[(b*CV+c)*MM+m] ; qv copy -> out[b][0:256]
#define KTOT 524288        // NB*MM*CK
#define VTOT 2097152       // NB*MM*CV
#define QTOT4 524288       // NB*CV*HH*WW/4 float4s
__global__ void pool_kv(const float* __restrict__ mk, const float* __restrict__ mv,
                        const float4* __restrict__ qv,
                        u16* __restrict__ pk, u16* __restrict__ vt,
                        float* __restrict__ out) {
    int e = blockIdx.x * 256 + threadIdx.x;
    if (e < KTOT) {
        int m = e & 4095; int c = (e >> 12) & 63; int b = e >> 18;
        int ww = m & 31, hh = (m >> 5) & 31, t = m >> 10;
        const float* s = mk + ((size_t)(((b*NT + t)*CK + c)*HH + 2*hh))*WW + 2*ww;
        pk[((size_t)b*MM + m)*CK + c] =
            f2b(fmaxf(fmaxf(s[0], s[1]), fmaxf(s[WW], s[WW+1])));
    } else if (e < KTOT + VTOT) {
        int e2 = e - KTOT;
        int m = e2 & 4095; int c = (e2 >> 12) & 255; int b = e2 >> 20;
        int ww = m & 31, hh = (m >> 5) & 31, t = m >> 10;
        const float* s = mv + ((size_t)(((b*NT + t)*CV + c)*HH + 2*hh))*WW + 2*ww;
        vt[((size_t)b*CV + c)*MM + m] =
            f2b(fmaxf(fmaxf(s[0], s[1]), fmaxf(s[WW], s[WW+1])));
    } else {
        int q = e - (KTOT + VTOT);           // [0, QTOT4)
        int b = q >> 18; int ru = q & 262143;
        ((float4*)out)[(size_t)b*(OUT_B/4) + ru] = qv[q];
    }
}

// Fused attention: grid (128 ntiles of 32 n, 2 b, 2 msplit) = 512 blocks,
// 512 threads = 8 waves -> 2 blocks/CU, 4 waves/SIMD.
// Per iter (128 m): QK: wave w owns m [16w,16w+16); PV: c in [32w,32w+32).
// Double-buffered P in LDS -> ONE barrier per iter.
__launch_bounds__(512, 4)
__global__ void attn_mfma(const u16* __restrict__ pk, const u16* __restrict__ vt,
                          const float* __restrict__ qk,
                          float* __restrict__ part, float* __restrict__ sums) {
    const int ntile = blockIdx.x, b = blockIdx.y, ms = blockIdx.z;
    const int tid = threadIdx.x, w = tid >> 6, l = tid & 63;
    const int lrow = l & 15, quad = l >> 4;
    const int n0 = ntile * 32;
    const int m0 = ms * MHALF;

    __shared__ u16  P[2][32 * 128];   // 2 x 8 KB, row = n_l (256 B), swizzled 8B chunks
    __shared__ float sums_s[8][32];

    // ---- Q B-fragments in registers: B[k=c][n]: n = n0+t*16+lrow, c = cc*32+quad*8+i
    bf16x8 qf[2][2];
    const float* qb = qk + (size_t)b * CK * NN;
    #pragma unroll
    for (int cc = 0; cc < 2; ++cc)
        #pragma unroll
        for (int t = 0; t < 2; ++t) {
            int n = n0 + t*16 + lrow;
            #pragma unroll
            for (int i = 0; i < 8; ++i) {
                int c = cc*32 + quad*8 + i;
                qf[cc][t][i] = (short)f2b(qb[(size_t)c*NN + n]);
            }
        }

    const u16* pkb = pk + (size_t)b * MM * CK;
    const u16* vtb = vt + (size_t)b * CV * MM;

    floatx4 oacc[2][2];               // [j: c-16-tile][t: n-16-tile]
    #pragma unroll
    for (int j = 0; j < 2; ++j)
        #pragma unroll
        for (int t = 0; t < 2; ++t)
            oacc[j][t] = (floatx4){0.f, 0.f, 0.f, 0.f};
    float sacc[2] = {0.f, 0.f};

    const int sw = lrow << 1;         // XOR swizzle key (even -> 16B pairs intact)

    for (int it = 0; it < ITERS; ++it) {
        const int mbase = m0 + it * 128;
        u16* Pb = &P[it & 1][0];

        // K A-frag: A[m][k=c]: m = mbase+16w+lrow, c = quad*8+i (+32)
        const u16* kp = pkb + (size_t)(mbase + w*16 + lrow)*CK + quad*8;
        bf16x8 kf0 = *(const bf16x8*)(kp);
        bf16x8 kf1 = *(const bf16x8*)(kp + 32);

        // ---- QK^T: S rows [16w,16w+16) x 32 n, exp, pack to LDS
        #pragma unroll
        for (int t = 0; t < 2; ++t) {
            floatx4 s = __builtin_amdgcn_mfma_f32_16x16x32_bf16(
                            kf0, qf[0][t], (floatx4){0.f,0.f,0.f,0.f}, 0, 0, 0);
            s = __builtin_amdgcn_mfma_f32_16x16x32_bf16(kf1, qf[1][t], s, 0, 0, 0);
            // C layout: n_l = t*16+lrow, m_l = 16w + quad*4 + r
            float p0 = __expf(s[0]*SCALE - SHIFT);
            float p1 = __expf(s[1]*SCALE - SHIFT);
            float p2 = __expf(s[2]*SCALE - SHIFT);
            float p3 = __expf(s[3]*SCALE - SHIFT);
            sacc[t] += (p0 + p1) + (p2 + p3);
            u32 d0 = (u32)f2b(p0) | ((u32)f2b(p1) << 16);
            u32 d1 = (u32)f2b(p2) | ((u32)f2b(p3) << 16);
            int n_l = t*16 + lrow;
            int cb  = (w << 2) + quad;            // logical 8B chunk = m_l>>2
            *(uint2*)&Pb[n_l*128 + ((cb ^ sw) << 2)] = make_uint2(d0, d1);
        }
        __syncthreads();

        // ---- PV: O[c][n] += V^T[c][m] * P[m][n]   (reads Pb; writes next go to other buf)
        #pragma unroll
        for (int cc = 0; cc < 4; ++cc) {
            const u16* vp = vtb + (size_t)(w*32 + lrow)*MM + mbase + cc*32 + quad*8;
            bf16x8 vf0 = *(const bf16x8*)(vp);                    // c = 32w+lrow
            bf16x8 vf1 = *(const bf16x8*)(vp + (size_t)16*MM);    // c = 32w+16+lrow
            int ch = (cc << 3) + (quad << 1);
            bf16x8 pf0 = *(const bf16x8*)&Pb[(lrow     )*128 + ((ch ^ sw) << 2)];
            bf16x8 pf1 = *(const bf16x8*)&Pb[(16 + lrow)*128 + ((ch ^ sw) << 2)];
            oacc[0][0] = __builtin_amdgcn_mfma_f32_16x16x32_bf16(vf0, pf0, oacc[0][0], 0,0,0);
            oacc[0][1] = __builtin_amdgcn_mfma_f32_16x16x32_bf16(vf0, pf1, oacc[0][1], 0,0,0);
            oacc[1][0] = __builtin_amdgcn_mfma_f32_16x16x32_bf16(vf1, pf0, oacc[1][0], 0,0,0);
            oacc[1][1] = __builtin_amdgcn_mfma_f32_16x16x32_bf16(vf1, pf1, oacc[1][1], 0,0,0);
        }
        // no trailing barrier: double-buffered P
    }

    // ---- sumexp: reduce over quad (same n), then over 8 waves via LDS
    #pragma unroll
    for (int t = 0; t < 2; ++t) {
        float v = sacc[t];
        v += __shfl_xor(v, 16, 64);
        v += __shfl_xor(v, 32, 64);
        if (l < 16) sums_s[w][t*16 + l] = v;
    }
    __syncthreads();

    // ---- write O partial tile [256c][32n]
    float* pb = part + ((size_t)((ms*NB + b)*128 + ntile)) * (256*32);
    #pragma unroll
    for (int j = 0; j < 2; ++j)
        #pragma unroll
        for (int t = 0; t < 2; ++t)
            #pragma unroll
            for (int r = 0; r < 4; ++r) {
                int c = w*32 + j*16 + quad*4 + r;
                int n = t*16 + lrow;
                pb[c*32 + n] = oacc[j][t][r];
            }
    if (tid < 32) {
        float sv = 0.f;
        #pragma unroll
        for (int ww2 = 0; ww2 < 8; ++ww2) sv += sums_s[ww2][tid];
        sums[((size_t)((ms*NB + b)*128 + ntile))*32 + tid] = sv;
    }
}

// epilogue: combine msplit partials, normalize, write memory half (float4)
__global__ void epilogue(const float* __restrict__ part, const float* __restrict__ sums,
                         float* __restrict__ out) {
    int e = blockIdx.x * 256 + threadIdx.x;      // 524288
    int nl4   = e & 7;
    int ntile = (e >> 3) & 127;
    int c     = (e >> 10) & 255;
    int b     = (e >> 18) & 1;
    size_t t0 = (size_t)(0*NB + b)*128 + ntile;
    size_t t1 = (size_t)(1*NB + b)*128 + ntile;
    const float4* p4 = (const float4*)part;
    const float4* s4 = (const float4*)sums;
    float4 u0 = p4[t0*2048 + c*8 + nl4];
    float4 u1 = p4[t1*2048 + c*8 + nl4];
    float4 d0 = s4[t0*8 + nl4];
    float4 d1 = s4[t1*8 + nl4];
    float4 r;
    r.x = (u0.x + u1.x) / (d0.x + d1.x);
    r.y = (u0.y + u1.y) / (d0.y + d1.y);
    r.z = (u0.z + u1.z) / (d0.z + d1.z);
    r.w = (u0.w + u1.w) / (d0.w + d1.w);
    ((float4*)out)[(size_t)(b*512 + 256 + c)*1024 + ntile*8 + nl4] = r;
}

// ======================= fallback (proven round-4) path =======================

__global__ void pool_v_f32(const float* __restrict__ src, float* __restrict__ out) {
    int e = blockIdx.x * 256 + threadIdx.x;
    int c = e & 255;
    int r = e >> 8;
    int ww = r & 31;  int hh = (r >> 5) & 31;
    int t  = (r >> 10) & 3;  int b = r >> 12;
    int m  = r & (MM - 1);
    const float* s = src + ((size_t)(((b*NT + t)*CV + c)*HH + 2*hh))*WW + 2*ww;
    out[(size_t)b*OUT_B + (size_t)m*CV + c] = fmaxf(fmaxf(s[0], s[1]), fmaxf(s[WW], s[WW+1]));
}

__global__ void pool_k_f32(const float* __restrict__ src, float* __restrict__ dst) {
    int e = blockIdx.x * 256 + threadIdx.x;
    int c = e & 63;
    int r = e >> 6;
    int ww = r & 31;  int hh = (r >> 5) & 31;
    int t  = (r >> 10) & 3;  int b = r >> 12;
    const float* s = src + ((size_t)(((b*NT + t)*CK + c)*HH + 2*hh))*WW + 2*ww;
    dst[e] = fmaxf(fmaxf(s[0], s[1]), fmaxf(s[WW], s[WW+1]));
}

__global__ void copy_qv_f32(const float4* __restrict__ src, float4* __restrict__ dst) {
    int u = blockIdx.x * 256 + threadIdx.x;
    int b  = u >> 18;
    int ru = u & 262143;
    dst[(size_t)b * (OUT_B/4) + ru] = src[u];
}

template<bool STAGED_K>
__launch_bounds__(256)
__global__ void attn_old(const float* __restrict__ pk,
                         const float* __restrict__ mk,
                         const float* __restrict__ qk,
                         float* __restrict__ out) {
    __shared__ __align__(16) float q_lds[CK][4];
    __shared__ __align__(16) float sarr[4][MM];
    __shared__ float inv_l[4];

    const int tid = threadIdx.x;
    const int blk = blockIdx.x;
    const int b   = blk >> 10;
    const int n0  = (blk & 1023) << 2;

    {
        int c = tid >> 2, qi = tid & 3;
        q_lds[c][qi] = qk[((size_t)(b*CK + c))*NN + n0 + qi];
    }
    __syncthreads();

    #pragma unroll
    for (int i = 0; i < 16; ++i) {
        int m = tid + (i << 8);
        float a0 = 0.f, a1 = 0.f, a2 = 0.f, a3 = 0.f;
        if (STAGED_K) {
            const float4* k4 = reinterpret_cast<const float4*>(pk + ((size_t)b*MM + m)*CK);
            #pragma unroll
            for (int cc = 0; cc < 16; ++cc) {
                float4 kv = k4[cc];
                int c = cc*4;
                float4 q0 = *reinterpret_cast<const float4*>(&q_lds[c][0]);
                float4 q1 = *reinterpret_cast<const float4*>(&q_lds[c+1][0]);
                float4 q2 = *reinterpret_cast<const float4*>(&q_lds[c+2][0]);
                float4 q3 = *reinterpret_cast<const float4*>(&q_lds[c+3][0]);
                a0 += kv.x*q0.x + kv.y*q1.x + kv.z*q2.x + kv.w*q3.x;
                a1 += kv.x*q0.y + kv.y*q1.y + kv.z*q2.y + kv.w*q3.y;
                a2 += kv.x*q0.z + kv.y*q1.z + kv.z*q2.z + kv.w*q3.z;
                a3 += kv.x*q0.w + kv.y*q1.w + kv.z*q2.w + kv.w*q3.w;
            }
        } else {
            int ww = m & 31, hh = (m >> 5) & 31, t = m >> 10;
            const float* base = mk + ((size_t)((b*NT + t)*CK)*HH + 2*hh)*WW + 2*ww;
            for (int c = 0; c < CK; ++c) {
                const float* s = base + (size_t)c*HH*WW;
                float kv = fmaxf(fmaxf(s[0], s[1]), fmaxf(s[WW], s[WW+1]));
                float4 q = *reinterpret_cast<const float4*>(&q_lds[c][0]);
                a0 += kv*q.x; a1 += kv*q.y; a2 += kv*q.z; a3 += kv*q.w;
            }
        }
        sarr[0][m] = a0*SCALE;
        sarr[1][m] = a1*SCALE;
        sarr[2][m] = a2*SCALE;
        sarr[3][m] = a3*SCALE;
    }
    __syncthreads();

    const int wave = tid >> 6, lane = tid & 63;
    float mx = -3.0e38f;
    for (int m = lane; m < MM; m += 64) mx = fmaxf(mx, sarr[wave][m]);
    #pragma unroll
    for (int off = 32; off > 0; off >>= 1) mx = fmaxf(mx, __shfl_xor(mx, off, 64));
    float ls = 0.f;
    for (int m = lane; m < MM; m += 64) {
        float p = __expf(sarr[wave][m] - mx);
        sarr[wave][m] = p;
        ls += p;
    }
    #pragma unroll
    for (int off = 32; off > 0; off >>= 1) ls += __shfl_xor(ls, off, 64);
    if (lane == 0) inv_l[wave] = 1.0f / ls;
    __syncthreads();

    const int c4 = lane;
    const float4* vb = reinterpret_cast<const float4*>(out + (size_t)b*OUT_B) + c4;
    const float* prow = sarr[wave];
    float a0 = 0.f, a1 = 0.f, a2 = 0.f, a3 = 0.f;
    for (int m = 0; m < MM; m += 4) {
        float4 p4 = *reinterpret_cast<const float4*>(prow + m);
        const float4* vp = vb + (size_t)m*(CV/4);
        float4 v0 = vp[0], v1 = vp[CV/4], v2 = vp[CV/2], v3 = vp[3*(CV/4)];
        a0 += p4.x*v0.x + p4.y*v1.x + p4.z*v2.x + p4.w*v3.x;
        a1 += p4.x*v0.y + p4.y*v1.y + p4.z*v2.y + p4.w*v3.y;
        a2 += p4.x*v0.z + p4.y*v1.z + p4.z*v2.z + p4.w*v3.z;
        a3 += p4.x*v0.w + p4.y*v1.w + p4.z*v2.w + p4.w*v3.w;
    }

    float inv = inv_l[wave];
    int n = n0 + wave;
    size_t ob = ((size_t)(b*512 + 256 + c4*4))*NN + n;
    out[ob]        = a0*inv;
    out[ob + NN]   = a1*inv;
    out[ob + 2*NN] = a2*inv;
    out[ob + 3*NN] = a3*inv;
}

// ================================ launcher ================================

extern "C" void kernel_launch(void* const* d_in, const int* in_sizes, int n_in,
                              void* d_out, int out_size, void* d_ws, size_t ws_size,
                              hipStream_t stream) {
    const float* mk = (const float*)d_in[0];
    const float* mv = (const float*)d_in[1];
    const float* qk = (const float*)d_in[2];
    const float* qv = (const float*)d_in[3];
    float* out = (float*)d_out;

    // fast-path ws layout: pk 1MB | vt 4MB | part 16MB | sums 64KB  (~21.07 MB)
    u16* pk_bf = (u16*)d_ws;
    u16* vt_bf = pk_bf + (size_t)NB*MM*CK;
    float* part = (float*)(vt_bf + (size_t)NB*CV*MM);
    float* sums = part + 4194304;
    const size_t need = (size_t)NB*MM*CK*2 + (size_t)NB*CV*MM*2
                      + (4194304 + 16384) * sizeof(float);

    if (ws_size >= need) {
        pool_kv<<<(KTOT + VTOT + QTOT4)/256, 256, 0, stream>>>(mk, mv, (const float4*)qv,
                                                               pk_bf, vt_bf, out);
        attn_mfma<<<dim3(128, NB, MSPLIT), 512, 0, stream>>>(pk_bf, vt_bf, qk, part, sums);
        epilogue<<<524288/256, 256, 0, stream>>>(part, sums, out);
    } else {
        const size_t pk_bytes = (size_t)NB*MM*CK*sizeof(float);
        const bool staged = (ws_size >= pk_bytes);
        float* pk = (float*)d_ws;
        pool_v_f32<<<(NB*MM*CV)/256, 256, 0, stream>>>(mv, out);
        if (staged) {
            pool_k_f32<<<(NB*MM*CK)/256, 256, 0, stream>>>(mk, pk);
            attn_old<true ><<<NB*(NN/4), 256, 0, stream>>>(pk, mk, qk, out);
        } else {
            attn_old<false><<<NB*(NN/4), 256, 0, stream>>>(pk, mk, qk, out);
        }
        copy_qv_f32<<<((NB*CV*HH*WW)/4)/256, 256, 0, stream>>>((const float4*)qv, (float4*)out);
    }
}

// Round 8
// 161.049 us; speedup vs baseline: 1.0955x; 1.0955x over previous
//
#include <hip/hip_runtime.h>
#include <hip/hip_bf16.h>

typedef unsigned short u16;
typedef unsigned int   u32;
typedef __attribute__((ext_vector_type(8))) short  bf16x8;
typedef __attribute__((ext_vector_type(4))) float  floatx4;

#define NB 2
#define NT 4
#define CK 64
#define CV 256
#define HH 64
#define WW 64
#define MM 4096    // NT*32*32
#define NN 4096    // HH*WW
#define SCALE 0.125f
#define SHIFT 4.0f
#define OUT_B 2097152      // f32 elems per batch in out (512*4096)

__device__ __forceinline__ u16 f2b(float f) {
    __hip_bfloat16 h = __float2bfloat16(f);
    union { __hip_bfloat16 h; u16 u; } v; v.h = h; return v.u;
}

// ============================ fast (MFMA) path ============================

// pooling by PAIRS (two adjacent output m share a 16B input row) + qv copy.
#define KP 262144          // K pooled-pairs  (NB*MM*CK/2)
#define VP 1048576         // V pooled-pairs  (NB*MM*CV/2)
#define QTOT4 524288       // qv float4s
__global__ void pool_kv(const float* __restrict__ mk, const float* __restrict__ mv,
                        const float4* __restrict__ qv,
                        u16* __restrict__ pk, u16* __restrict__ vt,
                        float* __restrict__ out) {
    int e = blockIdx.x * 256 + threadIdx.x;
    if (e < KP) {
        int q  = e & 15;          // pooled-pair col (covers ww 2q, 2q+1)
        int hh = (e >> 4) & 31;
        int t  = (e >> 9) & 3;
        int c  = (e >> 11) & 63;
        int b  = e >> 17;
        const float4* s = (const float4*)mk
                        + ((size_t)(((b*NT + t)*CK + c)*HH + 2*hh))*16 + q;
        float4 r0 = s[0], r1 = s[16];
        int m = t*1024 + hh*32 + 2*q;
        u16* d = pk + ((size_t)b*MM + m)*CK + c;
        d[0]  = f2b(fmaxf(fmaxf(r0.x, r0.y), fmaxf(r1.x, r1.y)));
        d[CK] = f2b(fmaxf(fmaxf(r0.z, r0.w), fmaxf(r1.z, r1.w)));
    } else if (e < KP + VP) {
        int e2 = e - KP;
        int q  = e2 & 15;
        int hh = (e2 >> 4) & 31;
        int t  = (e2 >> 9) & 3;
        int c  = (e2 >> 11) & 255;
        int b  = e2 >> 19;
        const float4* s = (const float4*)mv
                        + ((size_t)(((b*NT + t)*CV + c)*HH + 2*hh))*16 + q;
        float4 r0 = s[0], r1 = s[16];
        int m = t*1024 + hh*32 + 2*q;
        u32 lo = f2b(fmaxf(fmaxf(r0.x, r0.y), fmaxf(r1.x, r1.y)));
        u32 hi = f2b(fmaxf(fmaxf(r0.z, r0.w), fmaxf(r1.z, r1.w)));
        *(u32*)&vt[((size_t)b*CV + c)*MM + m] = lo | (hi << 16);
    } else {
        int e3 = e - (KP + VP);
        int b = e3 >> 18; int ru = e3 & 262143;
        ((float4*)out)[(size_t)b*(OUT_B/4) + ru] = qv[e3];
    }
}

// Fused attention. grid = dim3(NB*MSPLIT, 64): x -> (b = x&1, ms = x>>1),
// y = ntile (64 n each). 512 threads = 8 waves. linear block id % 8 == x,
// so each XCD sees one (b,ms) pair -> V working set 0.5 MB fits per-XCD L2.
// Per iter (128 m): wave w: QK rows m [16w,16w+16); PV channels [32w,32w+32).
// K/V fragments loaded at LOOP TOP (latency overlapped by QK/exp, drained by
// the single barrier); P double-buffered in LDS -> one barrier per iter.
template<int ITERS>
__launch_bounds__(512, 4)
__global__ void attn_mfma(const u16* __restrict__ pk, const u16* __restrict__ vt,
                          const float* __restrict__ qk,
                          float* __restrict__ part, float* __restrict__ sums) {
    const int ntile = blockIdx.y;
    const int b  = blockIdx.x & 1, ms = blockIdx.x >> 1;
    const int tid = threadIdx.x, w = tid >> 6, l = tid & 63;
    const int lrow = l & 15, quad = l >> 4;
    const int n0 = ntile * 64;
    const int m0 = ms * (ITERS * 128);

    __shared__ u16  P[2][64 * 128];   // 2 x 16 KB, row = n_l (256 B), swizzled 8B chunks
    __shared__ float sums_s[8][64];

    // ---- Q B-fragments in registers: B[k=c][n]: n = n0+t*16+lrow, c = cc*32+quad*8+i
    bf16x8 qf[2][4];
    const float* qb = qk + (size_t)b * CK * NN;
    #pragma unroll
    for (int cc = 0; cc < 2; ++cc)
        #pragma unroll
        for (int t = 0; t < 4; ++t) {
            int n = n0 + t*16 + lrow;
            #pragma unroll
            for (int i = 0; i < 8; ++i) {
                int c = cc*32 + quad*8 + i;
                qf[cc][t][i] = (short)f2b(qb[(size_t)c*NN + n]);
            }
        }

    const u16* pkb = pk + (size_t)b * MM * CK;
    const u16* vtb = vt + (size_t)b * CV * MM;

    floatx4 oacc[2][4];               // [j: c-16-tile][t: n-16-tile]
    #pragma unroll
    for (int j = 0; j < 2; ++j)
        #pragma unroll
        for (int t = 0; t < 4; ++t)
            oacc[j][t] = (floatx4){0.f, 0.f, 0.f, 0.f};
    float sacc[4] = {0.f, 0.f, 0.f, 0.f};

    const int sw = lrow << 1;         // XOR swizzle key (even -> 16B pairs intact)

    for (int it = 0; it < ITERS; ++it) {
        const int mbase = m0 + it * 128;
        u16* Pb = &P[it & 1][0];

        // K A-frag: A[m][k=c]: m = mbase+16w+lrow, c = quad*8+i (+32)
        const u16* kp = pkb + (size_t)(mbase + w*16 + lrow)*CK + quad*8;
        bf16x8 kf0 = *(const bf16x8*)(kp);
        bf16x8 kf1 = *(const bf16x8*)(kp + 32);

        // V A-frags AT TOP: A[c][k=m]: c = 32w+j*16+lrow, m = mbase+cc*32+quad*8+i
        bf16x8 vf[4][2];
        #pragma unroll
        for (int j = 0; j < 2; ++j) {
            const u16* vp = vtb + (size_t)(w*32 + j*16 + lrow)*MM + mbase + quad*8;
            vf[0][j] = *(const bf16x8*)(vp);
            vf[1][j] = *(const bf16x8*)(vp + 32);
            vf[2][j] = *(const bf16x8*)(vp + 64);
            vf[3][j] = *(const bf16x8*)(vp + 96);
        }

        // ---- QK^T: S rows [16w,16w+16) x 64 n, exp, pack to LDS
        #pragma unroll
        for (int t = 0; t < 4; ++t) {
            floatx4 s = __builtin_amdgcn_mfma_f32_16x16x32_bf16(
                            kf0, qf[0][t], (floatx4){0.f,0.f,0.f,0.f}, 0, 0, 0);
            s = __builtin_amdgcn_mfma_f32_16x16x32_bf16(kf1, qf[1][t], s, 0, 0, 0);
            // C layout: n_l = t*16+lrow, m_l = 16w + quad*4 + r
            float p0 = __expf(s[0]*SCALE - SHIFT);
            float p1 = __expf(s[1]*SCALE - SHIFT);
            float p2 = __expf(s[2]*SCALE - SHIFT);
            float p3 = __expf(s[3]*SCALE - SHIFT);
            sacc[t] += (p0 + p1) + (p2 + p3);
            u32 d0 = (u32)f2b(p0) | ((u32)f2b(p1) << 16);
            u32 d1 = (u32)f2b(p2) | ((u32)f2b(p3) << 16);
            int n_l = t*16 + lrow;
            int cb  = (w << 2) + quad;            // logical 8B chunk = m_l>>2
            *(uint2*)&Pb[n_l*128 + ((cb ^ sw) << 2)] = make_uint2(d0, d1);
        }
        __syncthreads();

        // ---- PV: O[c][n] += V^T[c][m] * P[m][n]  (V already in regs; P from LDS)
        #pragma unroll
        for (int cc = 0; cc < 4; ++cc) {
            bf16x8 pf[4];
            #pragma unroll
            for (int t = 0; t < 4; ++t) {
                int n_l = t*16 + lrow;
                int ch  = (cc << 3) + (quad << 1);
                pf[t] = *(const bf16x8*)&Pb[n_l*128 + ((ch ^ sw) << 2)];
            }
            #pragma unroll
            for (int j = 0; j < 2; ++j)
                #pragma unroll
                for (int t = 0; t < 4; ++t)
                    oacc[j][t] = __builtin_amdgcn_mfma_f32_16x16x32_bf16(
                                     vf[cc][j], pf[t], oacc[j][t], 0, 0, 0);
        }
        // no trailing barrier: double-buffered P
    }

    // ---- sumexp: reduce over quad (same n), then over 8 waves via LDS
    #pragma unroll
    for (int t = 0; t < 4; ++t) {
        float v = sacc[t];
        v += __shfl_xor(v, 16, 64);
        v += __shfl_xor(v, 32, 64);
        if (l < 16) sums_s[w][t*16 + l] = v;
    }
    __syncthreads();

    // ---- write O partial tile [256c][64n]
    float* pb = part + ((size_t)((ms*NB + b)*64 + ntile)) * (256*64);
    #pragma unroll
    for (int j = 0; j < 2; ++j)
        #pragma unroll
        for (int t = 0; t < 4; ++t)
            #pragma unroll
            for (int r = 0; r < 4; ++r) {
                int c = w*32 + j*16 + quad*4 + r;
                int n = t*16 + lrow;
                pb[c*64 + n] = oacc[j][t][r];
            }
    if (tid < 64) {
        float sv = 0.f;
        #pragma unroll
        for (int ww2 = 0; ww2 < 8; ++ww2) sv += sums_s[ww2][tid];
        sums[((size_t)((ms*NB + b)*64 + ntile))*64 + tid] = sv;
    }
}

// epilogue: combine MS msplit partials, normalize, write memory half (float4)
template<int MS>
__global__ void epilogue(const float* __restrict__ part, const float* __restrict__ sums,
                         float* __restrict__ out) {
    int e = blockIdx.x * 256 + threadIdx.x;      // 524288
    int nl4   = e & 15;
    int ntile = (e >> 4) & 63;
    int c     = (e >> 10) & 255;
    int b     = (e >> 18) & 1;
    const float4* p4 = (const float4*)part;
    const float4* s4 = (const float4*)sums;
    float4 num = {0.f,0.f,0.f,0.f}, den = {0.f,0.f,0.f,0.f};
    #pragma unroll
    for (int ms = 0; ms < MS; ++ms) {
        size_t ts = (size_t)(ms*NB + b)*64 + ntile;
        float4 u = p4[ts*4096 + c*16 + nl4];
        float4 d = s4[ts*16 + nl4];
        num.x += u.x; num.y += u.y; num.z += u.z; num.w += u.w;
        den.x += d.x; den.y += d.y; den.z += d.z; den.w += d.w;
    }
    float4 r;
    r.x = num.x/den.x; r.y = num.y/den.y; r.z = num.z/den.z; r.w = num.w/den.w;
    ((float4*)out)[(size_t)(b*512 + 256 + c)*1024 + ntile*16 + nl4] = r;
}

// ======================= fallback (proven round-4) path =======================

__global__ void pool_v_f32(const float* __restrict__ src, float* __restrict__ out) {
    int e = blockIdx.x * 256 + threadIdx.x;
    int c = e & 255;
    int r = e >> 8;
    int ww = r & 31;  int hh = (r >> 5) & 31;
    int t  = (r >> 10) & 3;  int b = r >> 12;
    int m  = r & (MM - 1);
    const float* s = src + ((size_t)(((b*NT + t)*CV + c)*HH + 2*hh))*WW + 2*ww;
    out[(size_t)b*OUT_B + (size_t)m*CV + c] = fmaxf(fmaxf(s[0], s[1]), fmaxf(s[WW], s[WW+1]));
}

__global__ void pool_k_f32(const float* __restrict__ src, float* __restrict__ dst) {
    int e = blockIdx.x * 256 + threadIdx.x;
    int c = e & 63;
    int r = e >> 6;
    int ww = r & 31;  int hh = (r >> 5) & 31;
    int t  = (r >> 10) & 3;  int b = r >> 12;
    const float* s = src + ((size_t)(((b*NT + t)*CK + c)*HH + 2*hh))*WW + 2*ww;
    dst[e] = fmaxf(fmaxf(s[0], s[1]), fmaxf(s[WW], s[WW+1]));
}

__global__ void copy_qv_f32(const float4* __restrict__ src, float4* __restrict__ dst) {
    int u = blockIdx.x * 256 + threadIdx.x;
    int b  = u >> 18;
    int ru = u & 262143;
    dst[(size_t)b * (OUT_B/4) + ru] = src[u];
}

template<bool STAGED_K>
__launch_bounds__(256)
__global__ void attn_old(const float* __restrict__ pk,
                         const float* __restrict__ mk,
                         const float* __restrict__ qk,
                         float* __restrict__ out) {
    __shared__ __align__(16) float q_lds[CK][4];
    __shared__ __align__(16) float sarr[4][MM];
    __shared__ float inv_l[4];

    const int tid = threadIdx.x;
    const int blk = blockIdx.x;
    const int b   = blk >> 10;
    const int n0  = (blk & 1023) << 2;

    {
        int c = tid >> 2, qi = tid & 3;
        q_lds[c][qi] = qk[((size_t)(b*CK + c))*NN + n0 + qi];
    }
    __syncthreads();

    #pragma unroll
    for (int i = 0; i < 16; ++i) {
        int m = tid + (i << 8);
        float a0 = 0.f, a1 = 0.f, a2 = 0.f, a3 = 0.f;
        if (STAGED_K) {
            const float4* k4 = reinterpret_cast<const float4*>(pk + ((size_t)b*MM + m)*CK);
            #pragma unroll
            for (int cc = 0; cc < 16; ++cc) {
                float4 kv = k4[cc];
                int c = cc*4;
                float4 q0 = *reinterpret_cast<const float4*>(&q_lds[c][0]);
                float4 q1 = *reinterpret_cast<const float4*>(&q_lds[c+1][0]);
                float4 q2 = *reinterpret_cast<const float4*>(&q_lds[c+2][0]);
                float4 q3 = *reinterpret_cast<const float4*>(&q_lds[c+3][0]);
                a0 += kv.x*q0.x + kv.y*q1.x + kv.z*q2.x + kv.w*q3.x;
                a1 += kv.x*q0.y + kv.y*q1.y + kv.z*q2.y + kv.w*q3.y;
                a2 += kv.x*q0.z + kv.y*q1.z + kv.z*q2.z + kv.w*q3.z;
                a3 += kv.x*q0.w + kv.y*q1.w + kv.z*q2.w + kv.w*q3.w;
            }
        } else {
            int ww = m & 31, hh = (m >> 5) & 31, t = m >> 10;
            const float* base = mk + ((size_t)((b*NT + t)*CK)*HH + 2*hh)*WW + 2*ww;
            for (int c = 0; c < CK; ++c) {
                const float* s = base + (size_t)c*HH*WW;
                float kv = fmaxf(fmaxf(s[0], s[1]), fmaxf(s[WW], s[WW+1]));
                float4 q = *reinterpret_cast<const float4*>(&q_lds[c][0]);
                a0 += kv*q.x; a1 += kv*q.y; a2 += kv*q.z; a3 += kv*q.w;
            }
        }
        sarr[0][m] = a0*SCALE;
        sarr[1][m] = a1*SCALE;
        sarr[2][m] = a2*SCALE;
        sarr[3][m] = a3*SCALE;
    }
    __syncthreads();

    const int wave = tid >> 6, lane = tid & 63;
    float mx = -3.0e38f;
    for (int m = lane; m < MM; m += 64) mx = fmaxf(mx, sarr[wave][m]);
    #pragma unroll
    for (int off = 32; off > 0; off >>= 1) mx = fmaxf(mx, __shfl_xor(mx, off, 64));
    float ls = 0.f;
    for (int m = lane; m < MM; m += 64) {
        float p = __expf(sarr[wave][m] - mx);
        sarr[wave][m] = p;
        ls += p;
    }
    #pragma unroll
    for (int off = 32; off > 0; off >>= 1) ls += __shfl_xor(ls, off, 64);
    if (lane == 0) inv_l[wave] = 1.0f / ls;
    __syncthreads();

    const int c4 = lane;
    const float4* vb = reinterpret_cast<const float4*>(out + (size_t)b*OUT_B) + c4;
    const float* prow = sarr[wave];
    float a0 = 0.f, a1 = 0.f, a2 = 0.f, a3 = 0.f;
    for (int m = 0; m < MM; m += 4) {
        float4 p4 = *reinterpret_cast<const float4*>(prow + m);
        const float4* vp = vb + (size_t)m*(CV/4);
        float4 v0 = vp[0], v1 = vp[CV/4], v2 = vp[CV/2], v3 = vp[3*(CV/4)];
        a0 += p4.x*v0.x + p4.y*v1.x + p4.z*v2.x + p4.w*v3.x;
        a1 += p4.x*v0.y + p4.y*v1.y + p4.z*v2.y + p4.w*v3.y;
        a2 += p4.x*v0.z + p4.y*v1.z + p4.z*v2.z + p4.w*v3.z;
        a3 += p4.x*v0.w + p4.y*v1.w + p4.z*v2.w + p4.w*v3.w;
    }

    float inv = inv_l[wave];
    int n = n0 + wave;
    size_t ob = ((size_t)(b*512 + 256 + c4*4))*NN + n;
    out[ob]        = a0*inv;
    out[ob + NN]   = a1*inv;
    out[ob + 2*NN] = a2*inv;
    out[ob + 3*NN] = a3*inv;
}

// ================================ launcher ================================

extern "C" void kernel_launch(void* const* d_in, const int* in_sizes, int n_in,
                              void* d_out, int out_size, void* d_ws, size_t ws_size,
                              hipStream_t stream) {
    const float* mk = (const float*)d_in[0];
    const float* mv = (const float*)d_in[1];
    const float* qk = (const float*)d_in[2];
    const float* qv = (const float*)d_in[3];
    float* out = (float*)d_out;

    // ws layout: pk 1MB | vt 4MB | part | sums
    u16* pk_bf = (u16*)d_ws;
    u16* vt_bf = pk_bf + (size_t)NB*MM*CK;
    float* part = (float*)(vt_bf + (size_t)NB*CV*MM);

    const size_t base   = (size_t)NB*MM*CK*2 + (size_t)NB*CV*MM*2;   // 5 MiB
    const size_t need_A = base + (8388608 + 32768) * sizeof(float);  // 38,928,384
    const size_t need_B = base + (4194304 + 16384) * sizeof(float);  // 22,085,632
    const int pool_blocks = (KP + VP + QTOT4) / 256;                 // 7168

    if (ws_size >= need_A) {
        float* sums = part + 8388608;
        pool_kv<<<pool_blocks, 256, 0, stream>>>(mk, mv, (const float4*)qv,
                                                 pk_bf, vt_bf, out);
        attn_mfma<8><<<dim3(8, 64), 512, 0, stream>>>(pk_bf, vt_bf, qk, part, sums);
        epilogue<4><<<524288/256, 256, 0, stream>>>(part, sums, out);
    } else if (ws_size >= need_B) {
        float* sums = part + 4194304;
        pool_kv<<<pool_blocks, 256, 0, stream>>>(mk, mv, (const float4*)qv,
                                                 pk_bf, vt_bf, out);
        attn_mfma<16><<<dim3(4, 64), 512, 0, stream>>>(pk_bf, vt_bf, qk, part, sums);
        epilogue<2><<<524288/256, 256, 0, stream>>>(part, sums, out);
    } else {
        const size_t pk_bytes = (size_t)NB*MM*CK*sizeof(float);
        const bool staged = (ws_size >= pk_bytes);
        float* pkf = (float*)d_ws;
        pool_v_f32<<<(NB*MM*CV)/256, 256, 0, stream>>>(mv, out);
        if (staged) {
            pool_k_f32<<<(NB*MM*CK)/256, 256, 0, stream>>>(mk, pkf);
            attn_old<true ><<<NB*(NN/4), 256, 0, stream>>>(pkf, mk, qk, out);
        } else {
            attn_old<false><<<NB*(NN/4), 256, 0, stream>>>(pkf, mk, qk, out);
        }
        copy_qv_f32<<<((NB*CV*HH*WW)/4)/256, 256, 0, stream>>>((const float4*)qv, (float4*)out);
    }
}

// Round 9
// 155.657 us; speedup vs baseline: 1.1335x; 1.0346x over previous
//
#include <hip/hip_runtime.h>
#include <hip/hip_bf16.h>

typedef unsigned short u16;
typedef unsigned int   u32;
typedef __attribute__((ext_vector_type(8))) short  bf16x8;
typedef __attribute__((ext_vector_type(4))) float  floatx4;

#define NB 2
#define NT 4
#define CK 64
#define CV 256
#define HH 64
#define WW 64
#define MM 4096    // NT*32*32
#define NN 4096    // HH*WW
#define VSTR 4128  // padded V^T row stride (8256 B != 2^k -> no L2 channel aliasing)
#define SCALE 0.125f
#define SHIFT 4.0f
#define OUT_B 2097152      // f32 elems per batch in out (512*4096)

__device__ __forceinline__ u16 f2b(float f) {
    __hip_bfloat16 h = __float2bfloat16(f);
    union { __hip_bfloat16 h; u16 u; } v; v.h = h; return v.u;
}

// ============================ fast (MFMA) path ============================
// pool K (bf16 m-major), pool V (bf16 c-major, PADDED rows), transpose Q to
// bf16 n-major, copy qv -> out. One kernel.
#define KP 262144          // K pooled-pairs  (NB*MM*CK/2)
#define VP 1048576         // V pooled-pairs  (NB*MM*CV/2)
#define QT 524288          // qt elems (NB*CK*NN)
#define QV4 524288         // qv float4s
__global__ void pool_kv(const float* __restrict__ mk, const float* __restrict__ mv,
                        const float* __restrict__ qk, const float4* __restrict__ qv,
                        u16* __restrict__ pk, u16* __restrict__ vt,
                        u16* __restrict__ qt, float* __restrict__ out) {
    int e = blockIdx.x * 256 + threadIdx.x;
    if (e < KP) {
        int q  = e & 15;          // pooled-pair col (covers ww 2q, 2q+1)
        int hh = (e >> 4) & 31;
        int t  = (e >> 9) & 3;
        int c  = (e >> 11) & 63;
        int b  = e >> 17;
        const float4* s = (const float4*)mk
                        + ((size_t)(((b*NT + t)*CK + c)*HH + 2*hh))*16 + q;
        float4 r0 = s[0], r1 = s[16];
        int m = t*1024 + hh*32 + 2*q;
        u16* d = pk + ((size_t)b*MM + m)*CK + c;
        d[0]  = f2b(fmaxf(fmaxf(r0.x, r0.y), fmaxf(r1.x, r1.y)));
        d[CK] = f2b(fmaxf(fmaxf(r0.z, r0.w), fmaxf(r1.z, r1.w)));
    } else if (e < KP + VP) {
        int e2 = e - KP;
        int q  = e2 & 15;
        int hh = (e2 >> 4) & 31;
        int t  = (e2 >> 9) & 3;
        int c  = (e2 >> 11) & 255;
        int b  = e2 >> 19;
        const float4* s = (const float4*)mv
                        + ((size_t)(((b*NT + t)*CV + c)*HH + 2*hh))*16 + q;
        float4 r0 = s[0], r1 = s[16];
        int m = t*1024 + hh*32 + 2*q;
        u32 lo = f2b(fmaxf(fmaxf(r0.x, r0.y), fmaxf(r1.x, r1.y)));
        u32 hi = f2b(fmaxf(fmaxf(r0.z, r0.w), fmaxf(r1.z, r1.w)));
        *(u32*)&vt[((size_t)b*CV + c)*VSTR + m] = lo | (hi << 16);
    } else if (e < KP + VP + QT) {
        int e3 = e - (KP + VP);
        int n = e3 & 4095;
        int c = (e3 >> 12) & 63;
        int b = e3 >> 18;
        qt[((size_t)b*NN + n)*CK + c] = f2b(qk[((size_t)(b*CK + c))*NN + n]);
    } else {
        int e4 = e - (KP + VP + QT);
        int b = e4 >> 18; int ru = e4 & 262143;
        ((float4*)out)[(size_t)b*(OUT_B/4) + ru] = qv[e4];
    }
}

// Fused single-pass attention. grid dim3(2, 128): x=b, y=ntile (32 n each).
// 512 thr = 8 waves, 1 block/CU. Full M loop (32 iters x 128 m).
// Wave w: QK rows m [16w,16w+16); PV channels [32w,32w+32).
// K/V register double-buffer: loads for it+1 issue right after it's barrier.
// P double-buffered in LDS -> one barrier per iter. Normalized write, no partials.
__launch_bounds__(512, 2)
__global__ void attn_fused(const u16* __restrict__ pk, const u16* __restrict__ vt,
                           const u16* __restrict__ qt, float* __restrict__ out) {
    const int b = blockIdx.x, ntile = blockIdx.y;
    const int tid = threadIdx.x, w = tid >> 6, l = tid & 63;
    const int lrow = l & 15, quad = l >> 4;
    const int n0 = ntile * 32;

    __shared__ u16  P[2][32 * 128];   // 2 x 8 KB, row = n_l (256 B), swizzled 8B chunks
    __shared__ float sums_s[8][32];

    // ---- Q B-fragments from staged qt [b][n][64c]: contiguous 16B reads
    bf16x8 qf[2][2];                  // [cc][t]
    {
        const u16* qtb = qt + (size_t)b * NN * CK;
        #pragma unroll
        for (int t = 0; t < 2; ++t) {
            const u16* qp = qtb + (size_t)(n0 + t*16 + lrow)*CK + quad*8;
            qf[0][t] = *(const bf16x8*)(qp);
            qf[1][t] = *(const bf16x8*)(qp + 32);
        }
    }

    const u16* pkb = pk + (size_t)b * MM * CK;
    const u16* vtb = vt + (size_t)b * CV * VSTR;

    floatx4 oacc[2][2];               // [j: c-16-tile][t: n-16-tile]
    #pragma unroll
    for (int j = 0; j < 2; ++j)
        #pragma unroll
        for (int t = 0; t < 2; ++t)
            oacc[j][t] = (floatx4){0.f, 0.f, 0.f, 0.f};
    float sacc[2] = {0.f, 0.f};

    const int sw = lrow << 1;         // XOR swizzle key (even -> 16B pairs intact)

    bf16x8 kf[2][2];                  // [slot][half]
    bf16x8 vf[2][4][2];               // [slot][cc][j]

    #define LOAD_K(it, s) {                                                   \
        const u16* kp = pkb + (size_t)((it)*128 + w*16 + lrow)*CK + quad*8;   \
        kf[s][0] = *(const bf16x8*)(kp);                                      \
        kf[s][1] = *(const bf16x8*)(kp + 32); }
    #define LOAD_V(it, s) {                                                   \
        _Pragma("unroll")                                                     \
        for (int j = 0; j < 2; ++j) {                                         \
            const u16* vp = vtb + (size_t)(w*32 + j*16 + lrow)*VSTR           \
                          + (it)*128 + quad*8;                                \
            vf[s][0][j] = *(const bf16x8*)(vp);                               \
            vf[s][1][j] = *(const bf16x8*)(vp + 32);                          \
            vf[s][2][j] = *(const bf16x8*)(vp + 64);                          \
            vf[s][3][j] = *(const bf16x8*)(vp + 96); } }

    LOAD_K(0, 0); LOAD_V(0, 0);

    #define PHASE(it, s, sn) {                                                \
        u16* Pb = &P[s][0];                                                   \
        _Pragma("unroll")                                                     \
        for (int t = 0; t < 2; ++t) {                                         \
            floatx4 sv = __builtin_amdgcn_mfma_f32_16x16x32_bf16(             \
                            kf[s][0], qf[0][t], (floatx4){0.f,0.f,0.f,0.f}, 0,0,0); \
            sv = __builtin_amdgcn_mfma_f32_16x16x32_bf16(kf[s][1], qf[1][t], sv, 0,0,0); \
            float p0 = __expf(sv[0]*SCALE - SHIFT);                           \
            float p1 = __expf(sv[1]*SCALE - SHIFT);                           \
            float p2 = __expf(sv[2]*SCALE - SHIFT);                           \
            float p3 = __expf(sv[3]*SCALE - SHIFT);                           \
            sacc[t] += (p0 + p1) + (p2 + p3);                                 \
            u32 d0 = (u32)f2b(p0) | ((u32)f2b(p1) << 16);                     \
            u32 d1 = (u32)f2b(p2) | ((u32)f2b(p3) << 16);                     \
            int cb = (w << 2) + quad;                                         \
            *(uint2*)&Pb[(t*16 + lrow)*128 + (((cb) ^ sw) << 2)]              \
                = make_uint2(d0, d1);                                         \
        }                                                                     \
        __syncthreads();                                                      \
        if ((it) + 1 < 32) { LOAD_K((it)+1, sn); LOAD_V((it)+1, sn); }        \
        _Pragma("unroll")                                                     \
        for (int cc = 0; cc < 4; ++cc) {                                      \
            int ch = (cc << 3) + (quad << 1);                                 \
            bf16x8 pf0 = *(const bf16x8*)&Pb[(lrow     )*128 + ((ch ^ sw) << 2)]; \
            bf16x8 pf1 = *(const bf16x8*)&Pb[(16 + lrow)*128 + ((ch ^ sw) << 2)]; \
            _Pragma("unroll")                                                 \
            for (int j = 0; j < 2; ++j) {                                     \
                oacc[j][0] = __builtin_amdgcn_mfma_f32_16x16x32_bf16(         \
                                 vf[s][cc][j], pf0, oacc[j][0], 0, 0, 0);     \
                oacc[j][1] = __builtin_amdgcn_mfma_f32_16x16x32_bf16(         \
                                 vf[s][cc][j], pf1, oacc[j][1], 0, 0, 0);     \
            }                                                                 \
        } }

    for (int it = 0; it < 32; it += 2) {
        PHASE(it,     0, 1);
        PHASE(it + 1, 1, 0);
    }
    #undef PHASE
    #undef LOAD_K
    #undef LOAD_V

    // ---- denominator: reduce over quad (same n), then over 8 waves via LDS
    #pragma unroll
    for (int t = 0; t < 2; ++t) {
        float v = sacc[t];
        v += __shfl_xor(v, 16, 64);
        v += __shfl_xor(v, 32, 64);
        if (l < 16) sums_s[w][t*16 + l] = v;
    }
    __syncthreads();

    float inv[2];
    #pragma unroll
    for (int t = 0; t < 2; ++t) {
        float sv = 0.f;
        #pragma unroll
        for (int w2 = 0; w2 < 8; ++w2) sv += sums_s[w2][t*16 + lrow];
        inv[t] = 1.0f / sv;
    }

    // ---- normalized final write: memory half of out
    float* ob = out + ((size_t)(b*512 + 256))*NN;
    #pragma unroll
    for (int j = 0; j < 2; ++j)
        #pragma unroll
        for (int t = 0; t < 2; ++t)
            #pragma unroll
            for (int r = 0; r < 4; ++r) {
                int c = w*32 + j*16 + quad*4 + r;
                int n = n0 + t*16 + lrow;
                ob[(size_t)c*NN + n] = oacc[j][t][r] * inv[t];
            }
}

// ======================= fallback (proven round-4) path =======================

__global__ void pool_v_f32(const float* __restrict__ src, float* __restrict__ out) {
    int e = blockIdx.x * 256 + threadIdx.x;
    int c = e & 255;
    int r = e >> 8;
    int ww = r & 31;  int hh = (r >> 5) & 31;
    int t  = (r >> 10) & 3;  int b = r >> 12;
    int m  = r & (MM - 1);
    const float* s = src + ((size_t)(((b*NT + t)*CV + c)*HH + 2*hh))*WW + 2*ww;
    out[(size_t)b*OUT_B + (size_t)m*CV + c] = fmaxf(fmaxf(s[0], s[1]), fmaxf(s[WW], s[WW+1]));
}

__global__ void pool_k_f32(const float* __restrict__ src, float* __restrict__ dst) {
    int e = blockIdx.x * 256 + threadIdx.x;
    int c = e & 63;
    int r = e >> 6;
    int ww = r & 31;  int hh = (r >> 5) & 31;
    int t  = (r >> 10) & 3;  int b = r >> 12;
    const float* s = src + ((size_t)(((b*NT + t)*CK + c)*HH + 2*hh))*WW + 2*ww;
    dst[e] = fmaxf(fmaxf(s[0], s[1]), fmaxf(s[WW], s[WW+1]));
}

__global__ void copy_qv_f32(const float4* __restrict__ src, float4* __restrict__ dst) {
    int u = blockIdx.x * 256 + threadIdx.x;
    int b  = u >> 18;
    int ru = u & 262143;
    dst[(size_t)b * (OUT_B/4) + ru] = src[u];
}

template<bool STAGED_K>
__launch_bounds__(256)
__global__ void attn_old(const float* __restrict__ pk,
                         const float* __restrict__ mk,
                         const float* __restrict__ qk,
                         float* __restrict__ out) {
    __shared__ __align__(16) float q_lds[CK][4];
    __shared__ __align__(16) float sarr[4][MM];
    __shared__ float inv_l[4];

    const int tid = threadIdx.x;
    const int blk = blockIdx.x;
    const int b   = blk >> 10;
    const int n0  = (blk & 1023) << 2;

    {
        int c = tid >> 2, qi = tid & 3;
        q_lds[c][qi] = qk[((size_t)(b*CK + c))*NN + n0 + qi];
    }
    __syncthreads();

    #pragma unroll
    for (int i = 0; i < 16; ++i) {
        int m = tid + (i << 8);
        float a0 = 0.f, a1 = 0.f, a2 = 0.f, a3 = 0.f;
        if (STAGED_K) {
            const float4* k4 = reinterpret_cast<const float4*>(pk + ((size_t)b*MM + m)*CK);
            #pragma unroll
            for (int cc = 0; cc < 16; ++cc) {
                float4 kv = k4[cc];
                int c = cc*4;
                float4 q0 = *reinterpret_cast<const float4*>(&q_lds[c][0]);
                float4 q1 = *reinterpret_cast<const float4*>(&q_lds[c+1][0]);
                float4 q2 = *reinterpret_cast<const float4*>(&q_lds[c+2][0]);
                float4 q3 = *reinterpret_cast<const float4*>(&q_lds[c+3][0]);
                a0 += kv.x*q0.x + kv.y*q1.x + kv.z*q2.x + kv.w*q3.x;
                a1 += kv.x*q0.y + kv.y*q1.y + kv.z*q2.y + kv.w*q3.y;
                a2 += kv.x*q0.z + kv.y*q1.z + kv.z*q2.z + kv.w*q3.z;
                a3 += kv.x*q0.w + kv.y*q1.w + kv.z*q2.w + kv.w*q3.w;
            }
        } else {
            int ww = m & 31, hh = (m >> 5) & 31, t = m >> 10;
            const float* base = mk + ((size_t)((b*NT + t)*CK)*HH + 2*hh)*WW + 2*ww;
            for (int c = 0; c < CK; ++c) {
                const float* s = base + (size_t)c*HH*WW;
                float kv = fmaxf(fmaxf(s[0], s[1]), fmaxf(s[WW], s[WW+1]));
                float4 q = *reinterpret_cast<const float4*>(&q_lds[c][0]);
                a0 += kv*q.x; a1 += kv*q.y; a2 += kv*q.z; a3 += kv*q.w;
            }
        }
        sarr[0][m] = a0*SCALE;
        sarr[1][m] = a1*SCALE;
        sarr[2][m] = a2*SCALE;
        sarr[3][m] = a3*SCALE;
    }
    __syncthreads();

    const int wave = tid >> 6, lane = tid & 63;
    float mx = -3.0e38f;
    for (int m = lane; m < MM; m += 64) mx = fmaxf(mx, sarr[wave][m]);
    #pragma unroll
    for (int off = 32; off > 0; off >>= 1) mx = fmaxf(mx, __shfl_xor(mx, off, 64));
    float ls = 0.f;
    for (int m = lane; m < MM; m += 64) {
        float p = __expf(sarr[wave][m] - mx);
        sarr[wave][m] = p;
        ls += p;
    }
    #pragma unroll
    for (int off = 32; off > 0; off >>= 1) ls += __shfl_xor(ls, off, 64);
    if (lane == 0) inv_l[wave] = 1.0f / ls;
    __syncthreads();

    const int c4 = lane;
    const float4* vb = reinterpret_cast<const float4*>(out + (size_t)b*OUT_B) + c4;
    const float* prow = sarr[wave];
    float a0 = 0.f, a1 = 0.f, a2 = 0.f, a3 = 0.f;
    for (int m = 0; m < MM; m += 4) {
        float4 p4 = *reinterpret_cast<const float4*>(prow + m);
        const float4* vp = vb + (size_t)m*(CV/4);
        float4 v0 = vp[0], v1 = vp[CV/4], v2 = vp[CV/2], v3 = vp[3*(CV/4)];
        a0 += p4.x*v0.x + p4.y*v1.x + p4.z*v2.x + p4.w*v3.x;
        a1 += p4.x*v0.y + p4.y*v1.y + p4.z*v2.y + p4.w*v3.y;
        a2 += p4.x*v0.z + p4.y*v1.z + p4.z*v2.z + p4.w*v3.z;
        a3 += p4.x*v0.w + p4.y*v1.w + p4.z*v2.w + p4.w*v3.w;
    }

    float inv = inv_l[wave];
    int n = n0 + wave;
    size_t ob = ((size_t)(b*512 + 256 + c4*4))*NN + n;
    out[ob]        = a0*inv;
    out[ob + NN]   = a1*inv;
    out[ob + 2*NN] = a2*inv;
    out[ob + 3*NN] = a3*inv;
}

// ================================ launcher ================================

extern "C" void kernel_launch(void* const* d_in, const int* in_sizes, int n_in,
                              void* d_out, int out_size, void* d_ws, size_t ws_size,
                              hipStream_t stream) {
    const float* mk = (const float*)d_in[0];
    const float* mv = (const float*)d_in[1];
    const float* qk = (const float*)d_in[2];
    const float* qv = (const float*)d_in[3];
    float* out = (float*)d_out;

    // ws layout: pk | vt (padded) | qt
    u16* pk_bf = (u16*)d_ws;                                   // 524288 u16
    u16* vt_bf = pk_bf + (size_t)NB*MM*CK;                     // 2,113,536 u16
    u16* qt_bf = vt_bf + (size_t)NB*CV*VSTR;                   // 524288 u16
    const size_t need = ((size_t)NB*MM*CK + (size_t)NB*CV*VSTR + (size_t)NB*NN*CK) * 2;

    if (ws_size >= need) {
        pool_kv<<<(KP + VP + QT + QV4)/256, 256, 0, stream>>>(
            mk, mv, qk, (const float4*)qv, pk_bf, vt_bf, qt_bf, out);
        attn_fused<<<dim3(2, 128), 512, 0, stream>>>(pk_bf, vt_bf, qt_bf, out);
    } else {
        const size_t pk_bytes = (size_t)NB*MM*CK*sizeof(float);
        const bool staged = (ws_size >= pk_bytes);
        float* pkf = (float*)d_ws;
        pool_v_f32<<<(NB*MM*CV)/256, 256, 0, stream>>>(mv, out);
        if (staged) {
            pool_k_f32<<<(NB*MM*CK)/256, 256, 0, stream>>>(mk, pkf);
            attn_old<true ><<<NB*(NN/4), 256, 0, stream>>>(pkf, mk, qk, out);
        } else {
            attn_old<false><<<NB*(NN/4), 256, 0, stream>>>(pkf, mk, qk, out);
        }
        copy_qv_f32<<<((NB*CV*HH*WW)/4)/256, 256, 0, stream>>>((const float4*)qv, (float4*)out);
    }
}